// Round 2
// baseline (608.839 us; speedup 1.0000x reference)
//
#include <hip/hip_runtime.h>

typedef unsigned short u16;
typedef unsigned int   u32;
typedef _Float16 f16x8 __attribute__((ext_vector_type(8)));
typedef float  f32x4  __attribute__((ext_vector_type(4)));
typedef float  f32x16 __attribute__((ext_vector_type(16)));
typedef int    i32x4  __attribute__((ext_vector_type(4)));
typedef u32    u32x2  __attribute__((ext_vector_type(2)));

#define Bn 8
#define Sn 96
#define Tn 96
#define Hn 64
#define H2n 128
#define STRB 152           // state row stride BYTES: 38 dwords, bank step 6 -> conflict-free b64
#define ARRB 16384         // padded array stride (96*152=14592 used) -> scalar parity fold
#define LDSB (8*ARRB)      // 131072 B: 2 dep x 2 stream x 2 parity
#define ODS 24320          // 95*Hn*4 : out byte stride per cell along a diagonal

__device__ __forceinline__ int imax(int a, int b){ return a > b ? a : b; }
__device__ __forceinline__ int imin(int a, int b){ return a < b ? a : b; }

__device__ __forceinline__ u32 pack2f16(float a, float b){
  _Float16 ha = (_Float16)a, hb = (_Float16)b;    // v_cvt_f16_f32 (RNE)
  return (u32)__builtin_bit_cast(u16, ha) | ((u32)__builtin_bit_cast(u16, hb) << 16);
}
// tanh(x) = 1 - 2/(e^{2x}+1). No clamp needed: exp2->inf => rcp->0 => 1;
// exp2->0 => -1. 5 VALU ops (mul, exp2, add, rcp, fma).
__device__ __forceinline__ float fast_tanh(float x){
  float e = exp2f(x * 2.88539008f);
  return __builtin_fmaf(-2.f, __builtin_amdgcn_rcpf(e + 1.f), 1.f);
}
__device__ __forceinline__ void barrier_lds_only(){
  asm volatile("s_waitcnt vmcnt(63) expcnt(7) lgkmcnt(0)\n\ts_barrier" ::: "memory");
}
// state B-fragment: 8 f16 (16B) as two b64 reads (8B-aligned; STRB=152 keeps
// bank accesses at the 128/32 minimum -> conflict-free)
__device__ __forceinline__ f16x8 ld_state(const char* p){
  u32x2 a = *(const u32x2*)(p);
  u32x2 b = *(const u32x2*)(p + 8);
  i32x4 v; v[0] = (int)a[0]; v[1] = (int)a[1]; v[2] = (int)b[0]; v[3] = (int)b[1];
  return __builtin_bit_cast(f16x8, v);
}

// Prologue: depth-0 input projections + bias, px[b,g,row,n] (fp32) into ws.
__global__ __launch_bounds__(64) void proj0_kernel(
  const float* __restrict__ src, const float* __restrict__ trg,
  const float* __restrict__ Wix, const float* __restrict__ Wiy,
  const float* __restrict__ bx, const float* __restrict__ by,
  float* __restrict__ ws)
{
  const int row = blockIdx.x, g = blockIdx.y, b = blockIdx.z;
  const int n = threadIdx.x;
  const float* x = (g == 0) ? (src + (b*Sn + row)*Hn) : (trg + (b*Tn + row)*Hn);
  const float* W = (g == 0) ? Wix : Wiy;
  float a = (g == 0) ? bx[n] : by[n];
  #pragma unroll 8
  for (int f = 0; f < Hn; ++f) a = fmaf(x[f], W[f*Hn + n], a);
  ws[((size_t)(b*2 + g)*Sn + row)*Hn + n] = a;
}

// Fused lag-1 wavefront, 512 threads = 8 waves: wave = (ct, g, dep).
// 32x32x16 MFMA; each wave covers ALL 64 output features of its stream via
// 2 M-tiles that SHARE one B-fragment -> state LDS reads cut 4x vs the
// 16-feature split. Cell tiles of 32; ct waves take tiles u = ct, ct+2.
// B frag: lane(cell=l&31, hi=l>>5): k = kk*16 + hi*8 + r. A frag: row=l&31,
// k = kk*16 + hi*8 + r. C/D: col=l&31, rowfeat = (reg&3)+8*(reg>>2)+4*hi.
// Valid-region only (rounds = sl+tl, diagonals clipped); invalid region
// pre-zeroed by memset. Clamped dead lanes read in-bounds zero-init state;
// their garbage columns are never stored.
__global__ __launch_bounds__(512, 2) void grid_rnn_fused(
  const float* __restrict__ Whx, const float* __restrict__ Why,
  const float* __restrict__ Wix, const float* __restrict__ Wiy,
  const float* __restrict__ bx,  const float* __restrict__ by,
  const int* __restrict__ src_lens, const int* __restrict__ trg_lens,
  float* __restrict__ out, const float* __restrict__ ws)
{
  extern __shared__ u16 smem[];
  char* const smemc = (char*)smem;
  const int b    = blockIdx.x;
  const int tid  = threadIdx.x;
  const int lane = tid & 63;
  const int wid  = __builtin_amdgcn_readfirstlane(tid >> 6);
  const int c32  = lane & 31;
  const int hi   = lane >> 5;
  const int dep  = wid & 1;
  const int g    = (wid >> 1) & 1;
  const int ct   = (wid >> 2) & 1;
  const int sl = __builtin_amdgcn_readfirstlane(src_lens[b]);
  const int tl = __builtin_amdgcn_readfirstlane(trg_lens[b]);
  const int NB = sl + tl;

  for (int idx = tid; idx < LDSB/4; idx += 512) ((u32*)smem)[idx] = 0u;

  // ---- weights: 8 k-steps x 2 M-tiles, fp16 fragments
  const float* Wh = (g == 0 ? Whx : Why) + dep*H2n*Hn;
  i32x4 whf[8][2];
  #pragma unroll
  for (int kk = 0; kk < 8; ++kk)
    #pragma unroll
    for (int mt = 0; mt < 2; ++mt)
      #pragma unroll
      for (int p = 0; p < 4; ++p){
        float w0 = Wh[(kk*16 + hi*8 + 2*p    )*Hn + mt*32 + c32];
        float w1 = Wh[(kk*16 + hi*8 + 2*p + 1)*Hn + mt*32 + c32];
        whf[kk][mt][p] = (int)pack2f16(w0, w1);
      }
  i32x4 wif[4][2];
  f32x16 biasr[2];
  if (dep == 1){
    const float* Wi = (g == 0 ? Wix : Wiy) + Hn*Hn;  // depth-1 slice
    #pragma unroll
    for (int kk = 0; kk < 4; ++kk)
      #pragma unroll
      for (int mt = 0; mt < 2; ++mt)
        #pragma unroll
        for (int p = 0; p < 4; ++p){
          float w0 = Wi[(kk*16 + hi*8 + 2*p    )*Hn + mt*32 + c32];
          float w1 = Wi[(kk*16 + hi*8 + 2*p + 1)*Hn + mt*32 + c32];
          wif[kk][mt][p] = (int)pack2f16(w0, w1);
        }
    const float* bb = (g == 0 ? bx : by) + Hn;       // depth-1 bias
    #pragma unroll
    for (int mt = 0; mt < 2; ++mt)
      #pragma unroll
      for (int reg = 0; reg < 16; ++reg)
        biasr[mt][reg] = bb[mt*32 + (reg & 3) + 8*(reg >> 2) + 4*hi];
  }
  const char* const pxb = (const char*)(ws + (size_t)(b*2 + g)*Sn*Hn);
  char* const outb = (char*)(out + (size_t)((g*2 + dep)*Bn + b)*(size_t)(Sn*Tn)*Hn);

  // per-lane address parts (bytes)
  const int plX  = -c32*STRB + hi*16;               // X reads: row j decreasing
  const int plY  =  c32*STRB + hi*16;               // Y reads: row i increasing
  const int plP  = g ? plY : plX;
  const int plW  = (g ? c32*STRB : -c32*STRB) + hi*8;
  const int plO  = c32*ODS + hi*16;
  const int plPx = (g ? -c32*256 : c32*256) + hi*16;

  const int depB  = dep*4*ARRB;                     // [X p0][X p1][Y p0][Y p1]
  const int basePg = g ? 2*ARRB : 0;                // dep0's X / Y pair
  const int baseWg = depB + (g ? 2*ARRB : 0);

  __syncthreads();

  for (int r = 0; r < NB; ++r){
    const int myd  = r - dep;
    const bool wact = (myd >= 0) && (myd <= NB - 2);
    const int cpB = (r & 1) ? ARRB : 0;
    const int ppB = ARRB - cpB;
    const int i0 = imax(0, myd - (tl - 1));
    const int i1 = imin(sl - 1, myd);
    const int nc = i1 - i0 + 1;
    const int mt32 = (nc + 31) >> 5;
    const int rJ0 = myd - i0, rJm = myd - i1;
    const int aX  = depB + ppB + rJ0*STRB;
    const int loX = depB + ppB + rJm*STRB;
    const int aY  = depB + 2*ARRB + ppB + i0*STRB;
    const int hiY = depB + 2*ARRB + ppB + i1*STRB + 16;
    const int aP  = basePg + ppB + (g ? i0 : rJ0)*STRB;
    const int loP = basePg + ppB + (g ? i0 : rJm)*STRB;
    const int hiP = basePg + ppB + (g ? i1 : rJ0)*STRB + 16;
    const int aW  = baseWg + cpB + (g ? i0 : rJ0)*STRB;
    const int sO  = myd*256 + i0*ODS;
    const int sPx = (g ? rJ0 : i0)*256;
    const int loPx= (g ? rJm : i0)*256;
    const int hiPx= (g ? rJ0 : i1)*256 + 16;

    #pragma unroll
    for (int t = 0; t < 2; ++t){
      const int u = ct + 2*t;
      if (!(wact && u < mt32)) continue;   // scalar branch
      const int cb = u*32;

      int vX = aX - cb*STRB + plX; vX = imax(vX, loX);
      int vY = aY + cb*STRB + plY; vY = imin(vY, hiY);

      f32x16 acc[2];
      if (dep == 0){
        int vp = sPx + (g ? -(cb*256) : cb*256) + plPx;
        vp = imin(imax(vp, loPx), hiPx);
        #pragma unroll
        for (int m = 0; m < 4; ++m){
          f32x4 t0 = *(const f32x4*)(pxb + (u32)vp + m*32);
          f32x4 t1 = *(const f32x4*)(pxb + (u32)vp + 128 + m*32);
          #pragma unroll
          for (int e = 0; e < 4; ++e){ acc[0][4*m+e] = t0[e]; acc[1][4*m+e] = t1[e]; }
        }
      } else {
        acc[0] = biasr[0]; acc[1] = biasr[1];
      }
      // recurrence K=128: kk 0..3 X (hx from col j), kk 4..7 Y (hy from row i)
      #pragma unroll
      for (int kk = 0; kk < 4; ++kk){
        f16x8 bv = ld_state(smemc + vX + kk*32);
        acc[0] = __builtin_amdgcn_mfma_f32_32x32x16_f16(
                   __builtin_bit_cast(f16x8, whf[kk][0]), bv, acc[0], 0, 0, 0);
        acc[1] = __builtin_amdgcn_mfma_f32_32x32x16_f16(
                   __builtin_bit_cast(f16x8, whf[kk][1]), bv, acc[1], 0, 0, 0);
      }
      #pragma unroll
      for (int kk = 0; kk < 4; ++kk){
        f16x8 bv = ld_state(smemc + vY + kk*32);
        acc[0] = __builtin_amdgcn_mfma_f32_32x32x16_f16(
                   __builtin_bit_cast(f16x8, whf[kk+4][0]), bv, acc[0], 0, 0, 0);
        acc[1] = __builtin_amdgcn_mfma_f32_32x32x16_f16(
                   __builtin_bit_cast(f16x8, whf[kk+4][1]), bv, acc[1], 0, 0, 0);
      }
      if (dep == 1){   // depth-1 projection from dep0's prev-parity state
        int vP = aP + (g ? cb*STRB : -(cb*STRB)) + plP;
        vP = imin(imax(vP, loP), hiP);
        #pragma unroll
        for (int kk = 0; kk < 4; ++kk){
          f16x8 pv = ld_state(smemc + vP + kk*32);
          acc[0] = __builtin_amdgcn_mfma_f32_32x32x16_f16(
                     __builtin_bit_cast(f16x8, wif[kk][0]), pv, acc[0], 0, 0, 0);
          acc[1] = __builtin_amdgcn_mfma_f32_32x32x16_f16(
                     __builtin_bit_cast(f16x8, wif[kk][1]), pv, acc[1], 0, 0, 0);
        }
      }
      // tanh -> state write (fp16, current parity) + out store (valid lanes)
      if (c32 < nc - cb){
        const int vW = aW + (g ? cb*STRB : -(cb*STRB)) + plW;
        const int vO = sO + cb*ODS + plO;
        #pragma unroll
        for (int mt = 0; mt < 2; ++mt)
          #pragma unroll
          for (int m = 0; m < 4; ++m){
            float h0 = fast_tanh(acc[mt][4*m+0]);
            float h1 = fast_tanh(acc[mt][4*m+1]);
            float h2 = fast_tanh(acc[mt][4*m+2]);
            float h3 = fast_tanh(acc[mt][4*m+3]);
            u32x2 hp; hp[0] = pack2f16(h0, h1); hp[1] = pack2f16(h2, h3);
            *(u32x2*)(smemc + vW + mt*64 + m*16) = hp;
            f32x4 ov = {h0, h1, h2, h3};
            *(f32x4*)(outb + (u32)vO + mt*128 + m*32) = ov;
          }
      }
    }
    barrier_lds_only();
  }
}

extern "C" void kernel_launch(void* const* d_in, const int* in_sizes, int n_in,
                              void* d_out, int out_size, void* d_ws, size_t ws_size,
                              hipStream_t stream) {
  (void)in_sizes; (void)n_in; (void)ws_size;
  (void)hipFuncSetAttribute((const void*)grid_rnn_fused,
                            hipFuncAttributeMaxDynamicSharedMemorySize, LDSB);
  (void)hipMemsetAsync(d_out, 0, (size_t)out_size, stream);
  proj0_kernel<<<dim3(Sn, 2, Bn), 64, 0, stream>>>(
      (const float*)d_in[0], (const float*)d_in[1],
      (const float*)d_in[2], (const float*)d_in[5],
      (const float*)d_in[4], (const float*)d_in[7],
      (float*)d_ws);
  grid_rnn_fused<<<dim3(Bn), dim3(512), LDSB, stream>>>(
      (const float*)d_in[3], (const float*)d_in[6],
      (const float*)d_in[2], (const float*)d_in[5],
      (const float*)d_in[4], (const float*)d_in[7],
      (const int*)d_in[8], (const int*)d_in[9],
      (float*)d_out, (const float*)d_ws);
}

// Round 3
// 594.192 us; speedup vs baseline: 1.0247x; 1.0247x over previous
//
#include <hip/hip_runtime.h>

typedef unsigned short u16;
typedef unsigned int   u32;
typedef _Float16 f16x8 __attribute__((ext_vector_type(8)));
typedef float  f32x2  __attribute__((ext_vector_type(2)));
typedef float  f32x4  __attribute__((ext_vector_type(4)));
typedef float  f32x16 __attribute__((ext_vector_type(16)));
typedef int    i32x4  __attribute__((ext_vector_type(4)));
typedef u32    u32x2  __attribute__((ext_vector_type(2)));

#define Bn 8
#define Sn 96
#define Tn 96
#define Hn 64
#define H2n 128
#define STRB 152           // state row stride BYTES: 19 u64, bank step 6 -> conflict-free b64
#define ARRB 16384         // padded array stride (96*152=14592 used) -> scalar parity fold
#define STATEB 131072      // 8 state arrays (2dep x 2stream x 2parity)
#define PXROW 152          // px row stride bytes (128 used), 8B-aligned, conflict-free
#define PXG   (Sn*PXROW)   // 14592
#define PXBASE STATEB
#define LDSB  (STATEB + 2*PXG)   // 160256 <= 163840
#define ODS 24320          // 95*Hn*4 : out byte stride per cell along a diagonal

__device__ __forceinline__ int imax(int a, int b){ return a > b ? a : b; }
__device__ __forceinline__ int imin(int a, int b){ return a < b ? a : b; }

__device__ __forceinline__ u32 pack2f16(float a, float b){
  _Float16 ha = (_Float16)a, hb = (_Float16)b;    // v_cvt_f16_f32 (RNE)
  return (u32)__builtin_bit_cast(u16, ha) | ((u32)__builtin_bit_cast(u16, hb) << 16);
}
__device__ __forceinline__ float f16tof(u32 v){
  return (float)__builtin_bit_cast(_Float16, (u16)v);
}
// tanh(x) = 1 - 2/(e^{2x}+1); exp2 overflow/underflow saturate correctly.
__device__ __forceinline__ float fast_tanh(float x){
  float e = exp2f(x * 2.88539008f);
  return __builtin_fmaf(-2.f, __builtin_amdgcn_rcpf(e + 1.f), 1.f);
}
__device__ __forceinline__ void barrier_lds_only(){
  asm volatile("s_waitcnt vmcnt(63) expcnt(7) lgkmcnt(0)\n\ts_barrier" ::: "memory");
}
// state B-fragment: 8 f16 (16B) as two b64 reads (8B-aligned at STRB=152)
__device__ __forceinline__ f16x8 ld_state(const char* p){
  u32x2 a = *(const u32x2*)(p);
  u32x2 b = *(const u32x2*)(p + 8);
  i32x4 v; v[0] = (int)a[0]; v[1] = (int)a[1]; v[2] = (int)b[0]; v[3] = (int)b[1];
  return __builtin_bit_cast(f16x8, v);
}

// Prologue: depth-0 input projections + bias, px[b,g,row,n] (fp32) into ws.
__global__ __launch_bounds__(64) void proj0_kernel(
  const float* __restrict__ src, const float* __restrict__ trg,
  const float* __restrict__ Wix, const float* __restrict__ Wiy,
  const float* __restrict__ bx, const float* __restrict__ by,
  float* __restrict__ ws)
{
  const int row = blockIdx.x, g = blockIdx.y, b = blockIdx.z;
  const int n = threadIdx.x;
  const float* x = (g == 0) ? (src + (b*Sn + row)*Hn) : (trg + (b*Tn + row)*Hn);
  const float* W = (g == 0) ? Wix : Wiy;
  float a = (g == 0) ? bx[n] : by[n];
  #pragma unroll 8
  for (int f = 0; f < Hn; ++f) a = fmaf(x[f], W[f*Hn + n], a);
  ws[((size_t)(b*2 + g)*Sn + row)*Hn + n] = a;
}

// Fused lag-1 wavefront, 1024 threads = 16 waves: wave = (ct, mt, g, dep).
// 32x32x16 MFMA; wave owns ONE 32-feature half (mt) of its (dep,g) stream
// -> ~110 VGPR, no spill, 4 waves/SIMD. Cell tiles of 32: u = ct, ct+2.
// A frag (weights): row=feat=lane&31, k=hi*8+e. B frag (state): col=cell=
// lane&31, k=hi*8+e. C/D: col=cell=lane&31, feat=(reg&3)+8*(reg>>2)+4*hi+32mt.
// OUT STORES DEFERRED: round r reads diag (r-1-dep) back from the previous-
// parity state buffer (lane=feature) and stores coalesced dwordx2 fp16->f32.
// px staged in LDS as fp16 (conflict-free 152B rows).
// Valid-region only; invalid region pre-zeroed by memset. Clamped dead lanes
// read in-bounds zero-init/garbage state; garbage columns never stored.
__global__ __launch_bounds__(1024, 1) void grid_rnn_fused(
  const float* __restrict__ Whx, const float* __restrict__ Why,
  const float* __restrict__ Wix, const float* __restrict__ Wiy,
  const float* __restrict__ bx,  const float* __restrict__ by,
  const int* __restrict__ src_lens, const int* __restrict__ trg_lens,
  float* __restrict__ out, const float* __restrict__ ws)
{
  extern __shared__ u16 smem[];
  char* const smemc = (char*)smem;
  const int b    = blockIdx.x;
  const int tid  = threadIdx.x;
  const int lane = tid & 63;
  const int wid  = __builtin_amdgcn_readfirstlane(tid >> 6);
  const int c32  = lane & 31;
  const int hi   = lane >> 5;
  const int dep  = wid & 1;
  const int g    = (wid >> 1) & 1;
  const int mt   = (wid >> 2) & 1;
  const int ct   = (wid >> 3) & 1;
  const int w4   = wid >> 2;          // 0..3 within (dep,g): readback slice
  const int sl = __builtin_amdgcn_readfirstlane(src_lens[b]);
  const int tl = __builtin_amdgcn_readfirstlane(trg_lens[b]);
  const int NB = sl + tl;

  for (int idx = tid; idx < STATEB/4; idx += 1024) ((u32*)smem)[idx] = 0u;

  // stage px: ws fp32 -> LDS fp16 (row stride 152B)
  {
    const int gp = tid >> 9;          // 0/1
    const int t5 = tid & 511;
    const float* wsg = ws + (size_t)(b*2 + gp)*Sn*Hn;
    #pragma unroll
    for (int it = 0; it < 6; ++it){
      int w = t5 + it*512;            // pair index 0..3071
      int row = w >> 5, pr = w & 31;
      f32x2 v = *(const f32x2*)(wsg + row*64 + pr*2);
      *(u32*)(smemc + PXBASE + gp*PXG + row*PXROW + pr*4) = pack2f16(v[0], v[1]);
    }
  }

  // ---- weights: 8 k-steps, ONE 32-feature tile (mt), fp16 A-fragments
  const float* Wh = (g == 0 ? Whx : Why) + dep*H2n*Hn;
  i32x4 whf[8];
  #pragma unroll
  for (int kk = 0; kk < 8; ++kk)
    #pragma unroll
    for (int p = 0; p < 4; ++p){
      float w0 = Wh[(kk*16 + hi*8 + 2*p    )*Hn + mt*32 + c32];
      float w1 = Wh[(kk*16 + hi*8 + 2*p + 1)*Hn + mt*32 + c32];
      whf[kk][p] = (int)pack2f16(w0, w1);
    }
  i32x4 wif[4];
  f32x16 biasr;
  if (dep == 1){
    const float* Wi = (g == 0 ? Wix : Wiy) + Hn*Hn;  // depth-1 slice
    #pragma unroll
    for (int kk = 0; kk < 4; ++kk)
      #pragma unroll
      for (int p = 0; p < 4; ++p){
        float w0 = Wi[(kk*16 + hi*8 + 2*p    )*Hn + mt*32 + c32];
        float w1 = Wi[(kk*16 + hi*8 + 2*p + 1)*Hn + mt*32 + c32];
        wif[kk][p] = (int)pack2f16(w0, w1);
      }
    const float* bb = (g == 0 ? bx : by) + Hn;       // depth-1 bias
    #pragma unroll
    for (int reg = 0; reg < 16; ++reg)
      biasr[reg] = bb[mt*32 + (reg & 3) + 8*(reg >> 2) + 4*hi];
  }
  char* const outb = (char*)(out + (size_t)((g*2 + dep)*Bn + b)*(size_t)(Sn*Tn)*Hn);

  // per-lane address parts (bytes)
  const int plX  = -c32*STRB + hi*16;               // X reads: row j decreasing
  const int plY  =  c32*STRB + hi*16;               // Y reads: row i increasing
  const int plP  = g ? plY : plX;
  const int plW  = (g ? c32*STRB : -c32*STRB) + mt*64 + hi*8;
  const int plPx = (g ? -c32*PXROW : c32*PXROW) + mt*64 + hi*8;
  const int plR  = (g ? hi*STRB : -hi*STRB) + c32*4;   // readback LDS part
  const int plO2 = hi*ODS + c32*8;                     // readback store part

  const int depB   = dep*4*ARRB;                    // [X p0][X p1][Y p0][Y p1]
  const int basePg = g ? 2*ARRB : 0;                // dep0's X / Y pair
  const int baseWg = depB + (g ? 2*ARRB : 0);

  __syncthreads();

  for (int r = 0; r < NB + 1; ++r){
    const int myd  = r - dep;
    const bool wact = (myd >= 0) && (myd <= NB - 2);
    const int cpB = (r & 1) ? ARRB : 0;
    const int ppB = ARRB - cpB;
    const int i0 = imax(0, myd - (tl - 1));
    const int i1 = imin(sl - 1, myd);
    const int nc = i1 - i0 + 1;
    const int mt32 = (nc + 31) >> 5;
    const int rJ0 = myd - i0, rJm = myd - i1;
    const int aX  = depB + ppB + rJ0*STRB;
    const int loX = depB + ppB + rJm*STRB;
    const int aY  = depB + 2*ARRB + ppB + i0*STRB;
    const int hiY = depB + 2*ARRB + ppB + i1*STRB + 16;
    const int aP  = basePg + ppB + (g ? i0 : rJ0)*STRB;
    const int loP = basePg + ppB + (g ? i0 : rJm)*STRB;
    const int hiP = basePg + ppB + (g ? i1 : rJ0)*STRB + 16;
    const int aW  = baseWg + cpB + (g ? i0 : rJ0)*STRB;
    const int aPx = PXBASE + g*PXG + (g ? rJ0 : i0)*PXROW;
    const int loPx= PXBASE + g*PXG + (g ? rJm : i0)*PXROW;
    const int hiPx= PXBASE + g*PXG + (g ? rJ0 : i1)*PXROW + 72;

    #pragma unroll
    for (int t = 0; t < 2; ++t){
      const int u = ct + 2*t;
      if (!(wact && u < mt32)) continue;   // scalar branch
      const int cb = u*32;

      int vX = aX - cb*STRB + plX; vX = imax(vX, loX);
      int vY = aY + cb*STRB + plY; vY = imin(vY, hiY);

      f32x16 acc;
      if (dep == 0){
        int vp = aPx + (g ? -(cb*PXROW) : cb*PXROW) + plPx;
        vp = imin(imax(vp, loPx), hiPx);
        #pragma unroll
        for (int m = 0; m < 4; ++m){
          u32x2 pv = *(const u32x2*)(smemc + vp + m*16);
          acc[4*m+0] = f16tof(pv[0] & 0xffffu);
          acc[4*m+1] = f16tof(pv[0] >> 16);
          acc[4*m+2] = f16tof(pv[1] & 0xffffu);
          acc[4*m+3] = f16tof(pv[1] >> 16);
        }
      } else {
        acc = biasr;
      }
      // recurrence K=128: kk 0..3 X (hx from col j), kk 4..7 Y (hy from row i)
      #pragma unroll
      for (int kk = 0; kk < 4; ++kk){
        f16x8 bv = ld_state(smemc + vX + kk*32);
        acc = __builtin_amdgcn_mfma_f32_32x32x16_f16(
                __builtin_bit_cast(f16x8, whf[kk]), bv, acc, 0, 0, 0);
      }
      #pragma unroll
      for (int kk = 0; kk < 4; ++kk){
        f16x8 bv = ld_state(smemc + vY + kk*32);
        acc = __builtin_amdgcn_mfma_f32_32x32x16_f16(
                __builtin_bit_cast(f16x8, whf[kk+4]), bv, acc, 0, 0, 0);
      }
      if (dep == 1){   // depth-1 projection from dep0's prev-parity state
        int vP = aP + (g ? cb*STRB : -(cb*STRB)) + plP;
        vP = imin(imax(vP, loP), hiP);
        #pragma unroll
        for (int kk = 0; kk < 4; ++kk){
          f16x8 pv = ld_state(smemc + vP + kk*32);
          acc = __builtin_amdgcn_mfma_f32_32x32x16_f16(
                  __builtin_bit_cast(f16x8, wif[kk]), pv, acc, 0, 0, 0);
        }
      }
      // tanh -> state write only (fp16, current parity); out deferred
      if (c32 < nc - cb){
        const int vW = aW + (g ? cb*STRB : -(cb*STRB)) + plW;
        #pragma unroll
        for (int m = 0; m < 4; ++m){
          float h0 = fast_tanh(acc[4*m+0]);
          float h1 = fast_tanh(acc[4*m+1]);
          float h2 = fast_tanh(acc[4*m+2]);
          float h3 = fast_tanh(acc[4*m+3]);
          u32x2 hp; hp[0] = pack2f16(h0, h1); hp[1] = pack2f16(h2, h3);
          *(u32x2*)(smemc + vW + m*16) = hp;
        }
      }
    }

    // ---- deferred out store: previous diag (r-1-dep) from prev-parity state,
    // lane = feature -> coalesced dwordx2 stores (full 64B lines).
    {
      const int dp = r - 1 - dep;
      if (dp >= 0 && dp <= NB - 2){
        const int i0p = imax(0, dp - (tl - 1));
        const int i1p = imin(sl - 1, dp);
        const int ncp = i1p - i0p + 1;
        const int arr = baseWg + ppB;     // own stream array, prev parity
        const int rb0 = arr + (g ? i0p : (dp - i0p))*STRB;
        const int rbnd = arr + (g ? (i1p*STRB + 124) : (dp - i1p)*STRB);
        const int sOp = (i0p*Tn + (dp - i0p))*256;
        for (int it = 0; it < 12; ++it){
          const int p = w4 + it*4;        // cell pair index
          if (2*p >= ncp) break;          // scalar
          int va = rb0 + (g ? (2*p)*STRB : -(2*p)*STRB) + plR;
          va = g ? imin(va, rbnd) : imax(va, rbnd);
          u32 sv = *(const u32*)(smemc + va);
          if (2*p + hi < ncp){
            f32x2 o2 = { f16tof(sv & 0xffffu), f16tof(sv >> 16) };
            *(f32x2*)(outb + (u32)(sOp + 2*p*ODS + plO2)) = o2;
          }
        }
      }
    }
    barrier_lds_only();
  }
}

extern "C" void kernel_launch(void* const* d_in, const int* in_sizes, int n_in,
                              void* d_out, int out_size, void* d_ws, size_t ws_size,
                              hipStream_t stream) {
  (void)in_sizes; (void)n_in; (void)ws_size;
  (void)hipFuncSetAttribute((const void*)grid_rnn_fused,
                            hipFuncAttributeMaxDynamicSharedMemorySize, LDSB);
  (void)hipMemsetAsync(d_out, 0, (size_t)out_size, stream);
  proj0_kernel<<<dim3(Sn, 2, Bn), 64, 0, stream>>>(
      (const float*)d_in[0], (const float*)d_in[1],
      (const float*)d_in[2], (const float*)d_in[5],
      (const float*)d_in[4], (const float*)d_in[7],
      (float*)d_ws);
  grid_rnn_fused<<<dim3(Bn), dim3(1024), LDSB, stream>>>(
      (const float*)d_in[3], (const float*)d_in[6],
      (const float*)d_in[2], (const float*)d_in[5],
      (const float*)d_in[4], (const float*)d_in[7],
      (const int*)d_in[8], (const int*)d_in[9],
      (float*)d_out, (const float*)d_ws);
}

// Round 5
// 580.441 us; speedup vs baseline: 1.0489x; 1.0237x over previous
//
#include <hip/hip_runtime.h>

typedef unsigned short u16;
typedef unsigned int   u32;
typedef _Float16 f16x8 __attribute__((ext_vector_type(8)));
typedef float  f32x2  __attribute__((ext_vector_type(2)));
typedef float  f32x4  __attribute__((ext_vector_type(4)));
typedef float  f32x16 __attribute__((ext_vector_type(16)));
typedef int    i32x4  __attribute__((ext_vector_type(4)));
typedef u32    u32x2  __attribute__((ext_vector_type(2)));

#define Bn 8
#define Sn 96
#define Tn 96
#define Hn 64
#define H2n 128
#define STRB 152           // state row stride BYTES: 19 u64, bank step 6 -> conflict-free b64
#define ARRB 16384         // padded array stride (96*152=14592 used) -> scalar parity fold
#define STATEB 131072      // 8 state arrays (2dep x 2stream x 2parity)
#define PXROW 152          // px row stride bytes (128 used)
#define PXG   (Sn*PXROW)   // 14592
#define PXBASE STATEB
#define LDSB  (STATEB + 2*PXG)   // 160256 <= 163840
#define ODS 24320          // 95*Hn*4 : out byte stride per cell along a diagonal

__device__ __forceinline__ int imax(int a, int b){ return a > b ? a : b; }
__device__ __forceinline__ int imin(int a, int b){ return a < b ? a : b; }

__device__ __forceinline__ u32 pack2f16(float a, float b){
  _Float16 ha = (_Float16)a, hb = (_Float16)b;    // v_cvt_f16_f32 (RNE)
  return (u32)__builtin_bit_cast(u16, ha) | ((u32)__builtin_bit_cast(u16, hb) << 16);
}
__device__ __forceinline__ float f16tof(u32 v){
  return (float)__builtin_bit_cast(_Float16, (u16)v);
}
// tanh(x) = 1 - 2/(e^{2x}+1); exp2 overflow/underflow saturate correctly.
__device__ __forceinline__ float fast_tanh(float x){
  float e = exp2f(x * 2.88539008f);
  return __builtin_fmaf(-2.f, __builtin_amdgcn_rcpf(e + 1.f), 1.f);
}
__device__ __forceinline__ void barrier_lds_only(){
  asm volatile("s_waitcnt vmcnt(63) expcnt(7) lgkmcnt(0)\n\ts_barrier" ::: "memory");
}
// state B-fragment: 8 f16 (16B) as two b64 reads (8B-aligned at STRB=152)
__device__ __forceinline__ f16x8 ld_state(const char* p){
  u32x2 a = *(const u32x2*)(p);
  u32x2 b = *(const u32x2*)(p + 8);
  i32x4 v; v[0] = (int)a[0]; v[1] = (int)a[1]; v[2] = (int)b[0]; v[3] = (int)b[1];
  return __builtin_bit_cast(f16x8, v);
}

// Prologue: depth-0 input projections + bias, px[b,g,row,n] (fp32) into ws.
__global__ __launch_bounds__(64) void proj0_kernel(
  const float* __restrict__ src, const float* __restrict__ trg,
  const float* __restrict__ Wix, const float* __restrict__ Wiy,
  const float* __restrict__ bx, const float* __restrict__ by,
  float* __restrict__ ws)
{
  const int row = blockIdx.x, g = blockIdx.y, b = blockIdx.z;
  const int n = threadIdx.x;
  const float* x = (g == 0) ? (src + (b*Sn + row)*Hn) : (trg + (b*Tn + row)*Hn);
  const float* W = (g == 0) ? Wix : Wiy;
  float a = (g == 0) ? bx[n] : by[n];
  #pragma unroll 8
  for (int f = 0; f < Hn; ++f) a = fmaf(x[f], W[f*Hn + n], a);
  ws[((size_t)(b*2 + g)*Sn + row)*Hn + n] = a;
}

// Fused lag-1 wavefront, 512 threads = 8 waves: wave = (ct, g, dep).
// 32x32x16 MFMA; wave covers ALL 64 output features (2 M-tiles SHARING each
// B-fragment -> state LDS reads halved vs 16-wave mt-split). launch_bounds
// (512,1): 2 waves/SIMD, 256-VGPR cap -> whole working set + staged B frags
// live in registers, no spill.
// A frag (weights): row=feat=lane&31 (+32mt), k=hi*8+e. B frag (state):
// col=cell=lane&31, k=hi*8+e. C/D: col=cell, feat=(reg&3)+8*(reg>>2)+4*hi+32mt.
// OUT STORES DEFERRED (coalesced): round r reads diag (r-1-dep) from the
// prev-parity state buffer; lane = (cell = k0+(lane>>3), feat octet lane&7):
// 8 cells/iter/wave at b64 reads + dwordx4 stores (R4 bug: 16-way lane split
// overran the 64-feature cell; fixed to 8-way).
// Valid-region only; invalid region pre-zeroed by memset; clamped dead lanes
// read in-bounds finite state, their columns never stored.
__global__ __launch_bounds__(512, 1) void grid_rnn_fused(
  const float* __restrict__ Whx, const float* __restrict__ Why,
  const float* __restrict__ Wix, const float* __restrict__ Wiy,
  const float* __restrict__ bx,  const float* __restrict__ by,
  const int* __restrict__ src_lens, const int* __restrict__ trg_lens,
  float* __restrict__ out, const float* __restrict__ ws)
{
  extern __shared__ u16 smem[];
  char* const smemc = (char*)smem;
  const int b    = blockIdx.x;
  const int tid  = threadIdx.x;
  const int lane = tid & 63;
  const int wid  = __builtin_amdgcn_readfirstlane(tid >> 6);
  const int c32  = lane & 31;
  const int hi   = lane >> 5;
  const int f16i = lane & 7;         // readback: feature-octet index (8 feats)
  const int k4   = lane >> 3;        // readback: cell offset 0..7
  const int dep  = wid & 1;
  const int g    = (wid >> 1) & 1;
  const int ct   = (wid >> 2) & 1;
  const int sl = __builtin_amdgcn_readfirstlane(src_lens[b]);
  const int tl = __builtin_amdgcn_readfirstlane(trg_lens[b]);
  const int NB = sl + tl;

  for (int idx = tid; idx < STATEB/16; idx += 512) ((i32x4*)smem)[idx] = (i32x4)(0);

  // stage px: ws fp32 -> LDS fp16 (row stride 152B)
  {
    const int gp = tid >> 8;          // 0/1 stream
    const int t5 = tid & 255;
    const float* wsg = ws + (size_t)(b*2 + gp)*Sn*Hn;
    #pragma unroll
    for (int it = 0; it < 12; ++it){
      int w = t5 + it*256;            // pair index 0..3071
      int row = w >> 5, pr = w & 31;
      f32x2 v = *(const f32x2*)(wsg + row*64 + pr*2);
      *(u32*)(smemc + PXBASE + gp*PXG + row*PXROW + pr*4) = pack2f16(v[0], v[1]);
    }
  }

  // ---- weights: 8 k-steps x 2 M-tiles, fp16 A-fragments
  const float* Wh = (g == 0 ? Whx : Why) + dep*H2n*Hn;
  i32x4 whf[8][2];
  #pragma unroll
  for (int kk = 0; kk < 8; ++kk)
    #pragma unroll
    for (int mt = 0; mt < 2; ++mt)
      #pragma unroll
      for (int p = 0; p < 4; ++p){
        float w0 = Wh[(kk*16 + hi*8 + 2*p    )*Hn + mt*32 + c32];
        float w1 = Wh[(kk*16 + hi*8 + 2*p + 1)*Hn + mt*32 + c32];
        whf[kk][mt][p] = (int)pack2f16(w0, w1);
      }
  i32x4 wif[4][2];
  f32x16 biasr[2];
  if (dep == 1){
    const float* Wi = (g == 0 ? Wix : Wiy) + Hn*Hn;  // depth-1 slice
    #pragma unroll
    for (int kk = 0; kk < 4; ++kk)
      #pragma unroll
      for (int mt = 0; mt < 2; ++mt)
        #pragma unroll
        for (int p = 0; p < 4; ++p){
          float w0 = Wi[(kk*16 + hi*8 + 2*p    )*Hn + mt*32 + c32];
          float w1 = Wi[(kk*16 + hi*8 + 2*p + 1)*Hn + mt*32 + c32];
          wif[kk][mt][p] = (int)pack2f16(w0, w1);
        }
    const float* bb = (g == 0 ? bx : by) + Hn;       // depth-1 bias
    #pragma unroll
    for (int mt = 0; mt < 2; ++mt)
      #pragma unroll
      for (int reg = 0; reg < 16; ++reg)
        biasr[mt][reg] = bb[mt*32 + (reg & 3) + 8*(reg >> 2) + 4*hi];
  }
  char* const outb = (char*)(out + (size_t)((g*2 + dep)*Bn + b)*(size_t)(Sn*Tn)*Hn);

  // per-lane address parts (bytes)
  const int plX  = -c32*STRB + hi*16;               // X reads: row j decreasing
  const int plY  =  c32*STRB + hi*16;               // Y reads: row i increasing
  const int plP  = g ? plY : plX;
  const int plW  = (g ? c32*STRB : -c32*STRB) + hi*8;
  const int plPx = (g ? -c32*PXROW : c32*PXROW) + hi*8;
  const int plRB = (g ? k4*STRB : -k4*STRB) + f16i*16;  // readback LDS part
  const int plF  = f16i*16;                             // readback bound part
  const int plRO = k4*ODS + f16i*32;                    // readback store part

  const int depB   = dep*4*ARRB;                    // [X p0][X p1][Y p0][Y p1]
  const int basePg = g ? 2*ARRB : 0;                // dep0's X / Y pair
  const int baseWg = depB + (g ? 2*ARRB : 0);

  __syncthreads();

  for (int r = 0; r < NB + 1; ++r){
    const int myd  = r - dep;
    const bool wact = (myd >= 0) && (myd <= NB - 2);
    const int cpB = (r & 1) ? ARRB : 0;
    const int ppB = ARRB - cpB;
    const int i0 = imax(0, myd - (tl - 1));
    const int i1 = imin(sl - 1, myd);
    const int nc = i1 - i0 + 1;
    const int mt32 = (nc + 31) >> 5;
    const int rJ0 = myd - i0, rJm = myd - i1;
    const int aX  = depB + ppB + rJ0*STRB;
    const int loX = depB + ppB + rJm*STRB;
    const int aY  = depB + 2*ARRB + ppB + i0*STRB;
    const int hiYb= depB + 2*ARRB + ppB + i1*STRB + 16;
    const int aP  = basePg + ppB + (g ? i0 : rJ0)*STRB;
    const int loP = basePg + ppB + (g ? i0 : rJm)*STRB;
    const int hiPb= basePg + ppB + (g ? i1 : rJ0)*STRB + 16;
    const int aW  = baseWg + cpB + (g ? i0 : rJ0)*STRB;
    const int aPx = PXBASE + g*PXG + (g ? rJ0 : i0)*PXROW;
    const int loPx= PXBASE + g*PXG + (g ? rJm : i0)*PXROW;
    const int hiPx= PXBASE + g*PXG + (g ? rJ0 : i1)*PXROW + 8;

    #pragma unroll
    for (int t = 0; t < 2; ++t){
      const int u = ct + 2*t;
      if (!(wact && u < mt32)) continue;   // scalar branch
      const int cb = u*32;

      int vX = aX - cb*STRB + plX; vX = imax(vX, loX);
      int vY = aY + cb*STRB + plY; vY = imin(vY, hiYb);

      // stage all B fragments first (256-VGPR budget allows it)
      f16x8 bvx[4], bvy[4];
      #pragma unroll
      for (int kk = 0; kk < 4; ++kk) bvx[kk] = ld_state(smemc + vX + kk*32);
      #pragma unroll
      for (int kk = 0; kk < 4; ++kk) bvy[kk] = ld_state(smemc + vY + kk*32);

      f32x16 a0, a1;
      if (dep == 0){
        int vp = aPx + (g ? -(cb*PXROW) : cb*PXROW) + plPx;
        vp = imin(imax(vp, loPx), hiPx);
        #pragma unroll
        for (int m = 0; m < 4; ++m){
          u32x2 p0 = *(const u32x2*)(smemc + vp + m*16);
          u32x2 p1 = *(const u32x2*)(smemc + vp + 64 + m*16);
          a0[4*m+0] = f16tof(p0[0] & 0xffffu); a0[4*m+1] = f16tof(p0[0] >> 16);
          a0[4*m+2] = f16tof(p0[1] & 0xffffu); a0[4*m+3] = f16tof(p0[1] >> 16);
          a1[4*m+0] = f16tof(p1[0] & 0xffffu); a1[4*m+1] = f16tof(p1[0] >> 16);
          a1[4*m+2] = f16tof(p1[1] & 0xffffu); a1[4*m+3] = f16tof(p1[1] >> 16);
        }
      } else {
        a0 = biasr[0]; a1 = biasr[1];
      }
      // recurrence K=128: kk 0..3 X (hx from col j), kk 4..7 Y (hy from row i)
      #pragma unroll
      for (int kk = 0; kk < 4; ++kk){
        a0 = __builtin_amdgcn_mfma_f32_32x32x16_f16(
               __builtin_bit_cast(f16x8, whf[kk][0]), bvx[kk], a0, 0, 0, 0);
        a1 = __builtin_amdgcn_mfma_f32_32x32x16_f16(
               __builtin_bit_cast(f16x8, whf[kk][1]), bvx[kk], a1, 0, 0, 0);
      }
      #pragma unroll
      for (int kk = 0; kk < 4; ++kk){
        a0 = __builtin_amdgcn_mfma_f32_32x32x16_f16(
               __builtin_bit_cast(f16x8, whf[kk+4][0]), bvy[kk], a0, 0, 0, 0);
        a1 = __builtin_amdgcn_mfma_f32_32x32x16_f16(
               __builtin_bit_cast(f16x8, whf[kk+4][1]), bvy[kk], a1, 0, 0, 0);
      }
      if (dep == 1){   // depth-1 projection from dep0's prev-parity state
        int vP = aP + (g ? cb*STRB : -(cb*STRB)) + plP;
        vP = imin(imax(vP, loP), hiPb);
        f16x8 pv[4];
        #pragma unroll
        for (int kk = 0; kk < 4; ++kk) pv[kk] = ld_state(smemc + vP + kk*32);
        #pragma unroll
        for (int kk = 0; kk < 4; ++kk){
          a0 = __builtin_amdgcn_mfma_f32_32x32x16_f16(
                 __builtin_bit_cast(f16x8, wif[kk][0]), pv[kk], a0, 0, 0, 0);
          a1 = __builtin_amdgcn_mfma_f32_32x32x16_f16(
                 __builtin_bit_cast(f16x8, wif[kk][1]), pv[kk], a1, 0, 0, 0);
        }
      }
      // tanh -> state write (fp16, current parity); out deferred to readback
      if (c32 < nc - cb){
        const int vW = aW + (g ? cb*STRB : -(cb*STRB)) + plW;
        #pragma unroll
        for (int m = 0; m < 4; ++m){
          float h0 = fast_tanh(a0[4*m+0]), h1 = fast_tanh(a0[4*m+1]);
          float h2 = fast_tanh(a0[4*m+2]), h3 = fast_tanh(a0[4*m+3]);
          u32x2 hp; hp[0] = pack2f16(h0, h1); hp[1] = pack2f16(h2, h3);
          *(u32x2*)(smemc + vW + m*16) = hp;
        }
        #pragma unroll
        for (int m = 0; m < 4; ++m){
          float h0 = fast_tanh(a1[4*m+0]), h1 = fast_tanh(a1[4*m+1]);
          float h2 = fast_tanh(a1[4*m+2]), h3 = fast_tanh(a1[4*m+3]);
          u32x2 hp; hp[0] = pack2f16(h0, h1); hp[1] = pack2f16(h2, h3);
          *(u32x2*)(smemc + vW + 64 + m*16) = hp;
        }
      }
    }

    // ---- deferred out store: diag (r-1-dep) from prev-parity state.
    // lane -> (cell = k0 + (lane>>3), feats = (lane&7)*8): b64 LDS reads,
    // dwordx4 stores, 8 cells per iteration per wave, 2 waves per (dep,g).
    {
      const int dp = r - 1 - dep;
      if (dp >= 0 && dp <= NB - 2){
        const int i0p = imax(0, dp - (tl - 1));
        const int i1p = imin(sl - 1, dp);
        const int ncp = i1p - i0p + 1;
        const int arr = baseWg + ppB;
        const int sA  = arr + (g ? i0p : (dp - i0p))*STRB;
        const int bndv = (g ? arr + i1p*STRB : arr + (dp - i1p)*STRB) + plF;
        const int sOp = (i0p*Tn + (dp - i0p))*256;
        for (int it = 0; it < 6; ++it){
          const int k0 = ct*8 + it*16;
          if (k0 >= ncp) break;           // scalar
          int va = sA + (g ? k0*STRB : -(k0*STRB)) + plRB;
          va = g ? imin(va, bndv) : imax(va, bndv);
          u32x2 s0 = *(const u32x2*)(smemc + va);
          u32x2 s1 = *(const u32x2*)(smemc + va + 8);
          if (k4 < ncp - k0){
            f32x4 o0 = { f16tof(s0[0] & 0xffffu), f16tof(s0[0] >> 16),
                         f16tof(s0[1] & 0xffffu), f16tof(s0[1] >> 16) };
            f32x4 o1 = { f16tof(s1[0] & 0xffffu), f16tof(s1[0] >> 16),
                         f16tof(s1[1] & 0xffffu), f16tof(s1[1] >> 16) };
            char* oa = outb + (u32)(sOp + k0*ODS + plRO);
            *(f32x4*)(oa) = o0;
            *(f32x4*)(oa + 16) = o1;
          }
        }
      }
    }
    barrier_lds_only();
  }
}

extern "C" void kernel_launch(void* const* d_in, const int* in_sizes, int n_in,
                              void* d_out, int out_size, void* d_ws, size_t ws_size,
                              hipStream_t stream) {
  (void)in_sizes; (void)n_in; (void)ws_size;
  (void)hipFuncSetAttribute((const void*)grid_rnn_fused,
                            hipFuncAttributeMaxDynamicSharedMemorySize, LDSB);
  (void)hipMemsetAsync(d_out, 0, (size_t)out_size, stream);
  proj0_kernel<<<dim3(Sn, 2, Bn), 64, 0, stream>>>(
      (const float*)d_in[0], (const float*)d_in[1],
      (const float*)d_in[2], (const float*)d_in[5],
      (const float*)d_in[4], (const float*)d_in[7],
      (float*)d_ws);
  grid_rnn_fused<<<dim3(Bn), dim3(512), LDSB, stream>>>(
      (const float*)d_in[3], (const float*)d_in[6],
      (const float*)d_in[2], (const float*)d_in[5],
      (const float*)d_in[4], (const float*)d_in[7],
      (const int*)d_in[8], (const int*)d_in[9],
      (float*)d_out, (const float*)d_ws);
}